// Round 1
// baseline (414.098 us; speedup 1.0000x reference)
//
#include <hip/hip_runtime.h>
#include <hip/hip_bf16.h>

// MHA: x[2,2048,1024]; q = x@w_k^T (faithful swap), k = x@w_q^T, v = x@w_v^T
// scores = QK^T * (1/sqrt(1024)), causal mask, softmax, ctx = P@V
// out = ctx@w_o^T + b_o   (fp32 out)

typedef __attribute__((ext_vector_type(8))) short bf16x8;
typedef __attribute__((ext_vector_type(4))) float f32x4;

#define SEQ 2048
#define NHEAD 16
#define HD 64
#define M_TOT 4096   // B*L

static __device__ __forceinline__ unsigned short f2bf(float f) {
  unsigned int u = __float_as_uint(f);
  u += 0x7fff + ((u >> 16) & 1);          // RNE
  return (unsigned short)(u >> 16);
}

static __device__ __forceinline__ void gload16(const unsigned short* g, unsigned short* l) {
  __builtin_amdgcn_global_load_lds(
      (const __attribute__((address_space(1))) unsigned int*)g,
      (__attribute__((address_space(3))) unsigned int*)l, 16, 0, 0);
}

// ---------------- fp32 -> bf16 convert, 4 elems/thread ----------------
__global__ void cvt_kernel(const float* __restrict__ in, unsigned short* __restrict__ out, int n) {
  int i = (blockIdx.x * blockDim.x + threadIdx.x) * 4;
  if (i >= n) return;
  float4 v = *reinterpret_cast<const float4*>(in + i);
  ushort4 o;
  o.x = f2bf(v.x); o.y = f2bf(v.y); o.z = f2bf(v.z); o.w = f2bf(v.w);
  *reinterpret_cast<ushort4*>(out + i) = o;
}

// ---------------- NT GEMM: C[M,N] = A[M,K] * B[N,K]^T ----------------
// 128x128 tile, 4 waves (2x2), BK=64, m97-style 2-barrier loop.
// mode 0: scatter to qb/kb ([b][h][l][d]) and vtb ([b][h][d][l]), bf16
// mode 1: out[m*1024+n] = acc + bias[n], fp32
__global__ __launch_bounds__(256) void gemm_nt(
    const unsigned short* __restrict__ A,
    const unsigned short* __restrict__ B,
    int K, int mode,
    unsigned short* __restrict__ qb,
    unsigned short* __restrict__ kb,
    unsigned short* __restrict__ vtb,
    const float* __restrict__ bias,
    float* __restrict__ outf)
{
  __shared__ unsigned short lds_a[128 * 64];
  __shared__ unsigned short lds_b[128 * 64];
  const int t = threadIdx.x;
  const int wid = t >> 6;
  const int lane = t & 63;
  const int lr = lane & 15;
  const int lg = lane >> 4;
  const int tm = blockIdx.x * 128;
  const int tn = blockIdx.y * 128;
  const int wr = (wid >> 1) * 64;
  const int wc = (wid & 1) * 64;

  const unsigned short* Ab = A + (size_t)tm * K;
  const unsigned short* Bb = B + (size_t)tn * K;
  const int srow = wid * 8 + (lane >> 3);   // row within a 32-row chunk
  const int scol = (lane & 7) * 8;          // bf16 col (16B granules)

  f32x4 acc[4][4];
  #pragma unroll
  for (int i = 0; i < 4; ++i)
    #pragma unroll
    for (int j = 0; j < 4; ++j) acc[i][j] = (f32x4){0.f, 0.f, 0.f, 0.f};

  for (int k0 = 0; k0 < K; k0 += 64) {
    #pragma unroll
    for (int i = 0; i < 4; ++i) {
      gload16(Ab + (size_t)(i * 32 + srow) * K + k0 + scol, &lds_a[(i * 32 + wid * 8) * 64]);
      gload16(Bb + (size_t)(i * 32 + srow) * K + k0 + scol, &lds_b[(i * 32 + wid * 8) * 64]);
    }
    __syncthreads();
    #pragma unroll
    for (int kk = 0; kk < 2; ++kk) {
      bf16x8 af[4], bfr[4];
      #pragma unroll
      for (int mi = 0; mi < 4; ++mi)
        af[mi] = *reinterpret_cast<const bf16x8*>(&lds_a[(wr + mi * 16 + lr) * 64 + kk * 32 + lg * 8]);
      #pragma unroll
      for (int ni = 0; ni < 4; ++ni)
        bfr[ni] = *reinterpret_cast<const bf16x8*>(&lds_b[(wc + ni * 16 + lr) * 64 + kk * 32 + lg * 8]);
      #pragma unroll
      for (int mi = 0; mi < 4; ++mi)
        #pragma unroll
        for (int ni = 0; ni < 4; ++ni)
          acc[mi][ni] = __builtin_amdgcn_mfma_f32_16x16x32_bf16(af[mi], bfr[ni], acc[mi][ni], 0, 0, 0);
    }
    __syncthreads();
  }

  if (mode == 0) {
    #pragma unroll
    for (int mi = 0; mi < 4; ++mi)
      #pragma unroll
      for (int ni = 0; ni < 4; ++ni)
        #pragma unroll
        for (int r = 0; r < 4; ++r) {
          int gm = tm + wr + mi * 16 + lg * 4 + r;
          int gn = tn + wc + ni * 16 + lr;
          float v = acc[mi][ni][r];
          unsigned short bv = f2bf(v);
          int bb = gm >> 11, l = gm & 2047;
          int tsel = gn >> 10, o = gn & 1023;
          int h = o >> 6, d = o & 63;
          if (tsel == 0)      qb[(((size_t)(bb * NHEAD + h)) * SEQ + l) * HD + d] = bv;
          else if (tsel == 1) kb[(((size_t)(bb * NHEAD + h)) * SEQ + l) * HD + d] = bv;
          else                vtb[(((size_t)(bb * NHEAD + h)) * HD + d) * SEQ + l] = bv;
        }
  } else {
    #pragma unroll
    for (int mi = 0; mi < 4; ++mi)
      #pragma unroll
      for (int ni = 0; ni < 4; ++ni)
        #pragma unroll
        for (int r = 0; r < 4; ++r) {
          int gm = tm + wr + mi * 16 + lg * 4 + r;
          int gn = tn + wc + ni * 16 + lr;
          outf[(size_t)gm * 1024 + gn] = acc[mi][ni][r] + bias[gn];
        }
  }
}

// ---------------- flash attention, causal ----------------
// grid (L/64, B*H), 256 threads. Wave w owns q-rows [q0+16w, q0+16w+16).
// KV tiles of 64. Q/K in [b][h][l][d] bf16; V transposed [b][h][d][l] bf16.
__global__ __launch_bounds__(256) void attn_kernel(
    const unsigned short* __restrict__ qb,
    const unsigned short* __restrict__ kb,
    const unsigned short* __restrict__ vtb,
    unsigned short* __restrict__ ctxb)
{
  __shared__ unsigned short p_lds[4][16 * 80];   // per-wave P tile, padded rows
  const int t = threadIdx.x;
  const int wid = t >> 6;
  const int lane = t & 63;
  const int lr = lane & 15;
  const int lg = lane >> 4;
  const int bh = blockIdx.y;
  const int b = bh >> 4, h = bh & 15;
  const int q0 = blockIdx.x * 64;
  const int qw = q0 + wid * 16;

  const float csc = (1.0f / 32.0f) * 1.44269504f;  // 1/sqrt(1024) * log2(e)

  // Q fragments (held in registers for the whole kernel)
  const unsigned short* Qp = qb + ((size_t)bh * SEQ + qw) * HD;
  bf16x8 aq[2];
  #pragma unroll
  for (int kk = 0; kk < 2; ++kk)
    aq[kk] = *reinterpret_cast<const bf16x8*>(&Qp[lr * HD + kk * 32 + lg * 8]);

  f32x4 oacc[4];
  #pragma unroll
  for (int ni = 0; ni < 4; ++ni) oacc[ni] = (f32x4){0.f, 0.f, 0.f, 0.f};
  float m_[4], ls[4];
  #pragma unroll
  for (int r = 0; r < 4; ++r) { m_[r] = -INFINITY; ls[r] = 0.f; }

  for (int kt = 0; kt <= (int)blockIdx.x; ++kt) {
    const int kv0 = kt * 64;
    const unsigned short* Kp = kb + ((size_t)bh * SEQ + kv0) * HD;

    // S = Q K^T  (scaled to base-2 domain)
    f32x4 s[4];
    #pragma unroll
    for (int ni = 0; ni < 4; ++ni) {
      s[ni] = (f32x4){0.f, 0.f, 0.f, 0.f};
      bf16x8 b0 = *reinterpret_cast<const bf16x8*>(&Kp[(ni * 16 + lr) * HD + 0 + lg * 8]);
      bf16x8 b1 = *reinterpret_cast<const bf16x8*>(&Kp[(ni * 16 + lr) * HD + 32 + lg * 8]);
      s[ni] = __builtin_amdgcn_mfma_f32_16x16x32_bf16(aq[0], b0, s[ni], 0, 0, 0);
      s[ni] = __builtin_amdgcn_mfma_f32_16x16x32_bf16(aq[1], b1, s[ni], 0, 0, 0);
    }

    float rmax[4];
    #pragma unroll
    for (int r = 0; r < 4; ++r) rmax[r] = -INFINITY;
    #pragma unroll
    for (int ni = 0; ni < 4; ++ni)
      #pragma unroll
      for (int r = 0; r < 4; ++r) {
        int kv = kv0 + ni * 16 + lr;
        int qr = qw + lg * 4 + r;
        float y = s[ni][r] * csc;
        if (kv > qr) y = -INFINITY;           // causal
        s[ni][r] = y;
        rmax[r] = fmaxf(rmax[r], y);
      }
    #pragma unroll
    for (int off = 1; off < 16; off <<= 1)
      #pragma unroll
      for (int r = 0; r < 4; ++r) rmax[r] = fmaxf(rmax[r], __shfl_xor(rmax[r], off));

    float f[4], psum[4];
    #pragma unroll
    for (int r = 0; r < 4; ++r) {
      float mn = fmaxf(m_[r], rmax[r]);
      f[r] = exp2f(m_[r] - mn);
      m_[r] = mn;
      psum[r] = 0.f;
    }
    #pragma unroll
    for (int ni = 0; ni < 4; ++ni)
      #pragma unroll
      for (int r = 0; r < 4; ++r) {
        float p = exp2f(s[ni][r] - m_[r]);
        psum[r] += p;
        p_lds[wid][(lg * 4 + r) * 80 + ni * 16 + lr] = f2bf(p);
      }
    #pragma unroll
    for (int off = 1; off < 16; off <<= 1)
      #pragma unroll
      for (int r = 0; r < 4; ++r) psum[r] += __shfl_xor(psum[r], off);
    #pragma unroll
    for (int r = 0; r < 4; ++r) ls[r] = ls[r] * f[r] + psum[r];
    #pragma unroll
    for (int ni = 0; ni < 4; ++ni)
      #pragma unroll
      for (int r = 0; r < 4; ++r) oacc[ni][r] *= f[r];

    __syncthreads();   // P writes visible (and lgkmcnt drained)

    // ctx += P V : A = P [16 x 64] from LDS, B = Vt rows (d), K-contig in kv
    bf16x8 pa0 = *reinterpret_cast<const bf16x8*>(&p_lds[wid][lr * 80 + 0 + lg * 8]);
    bf16x8 pa1 = *reinterpret_cast<const bf16x8*>(&p_lds[wid][lr * 80 + 32 + lg * 8]);
    const unsigned short* Vp = vtb + (size_t)bh * HD * SEQ + kv0;
    #pragma unroll
    for (int ni = 0; ni < 4; ++ni) {
      bf16x8 v0 = *reinterpret_cast<const bf16x8*>(&Vp[(size_t)(ni * 16 + lr) * SEQ + 0 + lg * 8]);
      bf16x8 v1 = *reinterpret_cast<const bf16x8*>(&Vp[(size_t)(ni * 16 + lr) * SEQ + 32 + lg * 8]);
      oacc[ni] = __builtin_amdgcn_mfma_f32_16x16x32_bf16(pa0, v0, oacc[ni], 0, 0, 0);
      oacc[ni] = __builtin_amdgcn_mfma_f32_16x16x32_bf16(pa1, v1, oacc[ni], 0, 0, 0);
    }
    __syncthreads();   // P reads done before next tile overwrites
  }

  // write ctx [b][l][h*64+d] bf16
  #pragma unroll
  for (int ni = 0; ni < 4; ++ni)
    #pragma unroll
    for (int r = 0; r < 4; ++r) {
      int qr = qw + lg * 4 + r;
      int d = ni * 16 + lr;
      ctxb[((size_t)b * SEQ + qr) * 1024 + h * HD + d] = f2bf(oacc[ni][r] / ls[r]);
    }
}

extern "C" void kernel_launch(void* const* d_in, const int* in_sizes, int n_in,
                              void* d_out, int out_size, void* d_ws, size_t ws_size,
                              hipStream_t stream) {
  const float* x   = (const float*)d_in[0];
  const float* w_k = (const float*)d_in[1];
  const float* w_q = (const float*)d_in[2];
  const float* w_v = (const float*)d_in[3];
  const float* w_o = (const float*)d_in[4];
  const float* b_o = (const float*)d_in[5];
  float* out = (float*)d_out;

  char* ws = (char*)d_ws;
  unsigned short* xb   = (unsigned short*)(ws + 0);          //  8 MB [4096][1024]
  unsigned short* wqkv = (unsigned short*)(ws + 8388608);    //  6 MB [3072][1024]  (w_k;w_q;w_v)
  unsigned short* wob  = (unsigned short*)(ws + 14680064);   //  2 MB [1024][1024]
  unsigned short* qb   = (unsigned short*)(ws + 16777216);   //  8 MB [b][h][l][d]
  unsigned short* kb   = (unsigned short*)(ws + 25165824);   //  8 MB [b][h][l][d]
  unsigned short* vtb  = (unsigned short*)(ws + 33554432);   //  8 MB [b][h][d][l]
  unsigned short* ctxb = xb;                                  // reuse x region

  int n = M_TOT * 1024;
  cvt_kernel<<<n / 1024, 256, 0, stream>>>(x, xb, n);
  n = 1024 * 1024;
  cvt_kernel<<<n / 1024, 256, 0, stream>>>(w_k, wqkv, n);
  cvt_kernel<<<n / 1024, 256, 0, stream>>>(w_q, wqkv + 1048576, n);
  cvt_kernel<<<n / 1024, 256, 0, stream>>>(w_v, wqkv + 2097152, n);
  cvt_kernel<<<n / 1024, 256, 0, stream>>>(w_o, wob, n);

  // QKV: A = xb [4096][1024], B = wqkv [3072][1024]  (col block 0 -> Q via w_k, 1 -> K via w_q, 2 -> V)
  gemm_nt<<<dim3(32, 24), 256, 0, stream>>>(xb, wqkv, 1024, 0, qb, kb, vtb, nullptr, nullptr);

  attn_kernel<<<dim3(SEQ / 64, 2 * NHEAD), 256, 0, stream>>>(qb, kb, vtb, ctxb);

  // out = ctx @ w_o^T + b_o
  gemm_nt<<<dim3(32, 8), 256, 0, stream>>>(ctxb, wob, 1024, 1, nullptr, nullptr, nullptr, b_o, out);
}

// Round 4
// 261.964 us; speedup vs baseline: 1.5807x; 1.5807x over previous
//
#include <hip/hip_runtime.h>
#include <hip/hip_bf16.h>

// MHA: x[2,2048,1024]; q = x@w_k^T (faithful swap), k = x@w_q^T, v = x@w_v^T
// scores = QK^T * (1/sqrt(1024)), causal mask, softmax, ctx = P@V
// out = ctx@w_o^T + b_o   (fp32 out)

typedef __attribute__((ext_vector_type(8))) short bf16x8;
typedef __attribute__((ext_vector_type(4))) float f32x4;

#define SEQ 2048
#define NHEAD 16
#define HD 64
#define M_TOT 4096   // B*L

static __device__ __forceinline__ unsigned short f2bf(float f) {
  unsigned int u = __float_as_uint(f);
  u += 0x7fff + ((u >> 16) & 1);          // RNE
  return (unsigned short)(u >> 16);
}
static __device__ __forceinline__ float bf2f(unsigned short u) {
  return __uint_as_float(((unsigned int)u) << 16);
}

static __device__ __forceinline__ void gload16(const unsigned short* g, unsigned short* l) {
  __builtin_amdgcn_global_load_lds(
      (const __attribute__((address_space(1))) unsigned int*)g,
      (__attribute__((address_space(3))) unsigned int*)l, 16, 0, 0);
}

// ---------------- fp32 -> bf16 convert, 4 elems/thread ----------------
__global__ void cvt_kernel(const float* __restrict__ in, unsigned short* __restrict__ out, int n) {
  int i = (blockIdx.x * blockDim.x + threadIdx.x) * 4;
  if (i >= n) return;
  float4 v = *reinterpret_cast<const float4*>(in + i);
  ushort4 o;
  o.x = f2bf(v.x); o.y = f2bf(v.y); o.z = f2bf(v.z); o.w = f2bf(v.w);
  *reinterpret_cast<ushort4*>(out + i) = o;
}

// ---------------- NT GEMM: C[M,N] = A[M,K] * B[N,K]^T ----------------
// 128x128 tile, 4 waves (2x2), BK=64, m97-style 2-barrier loop.
// mode 0: scatter to qb/kb ([b][h][l][d]) and vtb ([b][h][d][l]), bf16
// mode 1: out[m*1024+n] = acc + bias[n], fp32
__global__ __launch_bounds__(256) void gemm_nt(
    const unsigned short* __restrict__ A,
    const unsigned short* __restrict__ B,
    int K, int mode,
    unsigned short* __restrict__ qb,
    unsigned short* __restrict__ kb,
    unsigned short* __restrict__ vtb,
    const float* __restrict__ bias,
    float* __restrict__ outf)
{
  __shared__ unsigned short lds_a[128 * 64];
  __shared__ unsigned short lds_b[128 * 64];
  const int t = threadIdx.x;
  const int wid = t >> 6;
  const int lane = t & 63;
  const int lr = lane & 15;
  const int lg = lane >> 4;
  const int tm = blockIdx.x * 128;
  const int tn = blockIdx.y * 128;
  const int wr = (wid >> 1) * 64;
  const int wc = (wid & 1) * 64;

  const unsigned short* Ab = A + (size_t)tm * K;
  const unsigned short* Bb = B + (size_t)tn * K;
  const int srow = wid * 8 + (lane >> 3);   // row within a 32-row chunk
  const int scol = (lane & 7) * 8;          // bf16 col (16B granules)

  f32x4 acc[4][4];
  #pragma unroll
  for (int i = 0; i < 4; ++i)
    #pragma unroll
    for (int j = 0; j < 4; ++j) acc[i][j] = (f32x4){0.f, 0.f, 0.f, 0.f};

  for (int k0 = 0; k0 < K; k0 += 64) {
    #pragma unroll
    for (int i = 0; i < 4; ++i) {
      gload16(Ab + (size_t)(i * 32 + srow) * K + k0 + scol, &lds_a[(i * 32 + wid * 8) * 64]);
      gload16(Bb + (size_t)(i * 32 + srow) * K + k0 + scol, &lds_b[(i * 32 + wid * 8) * 64]);
    }
    __syncthreads();
    #pragma unroll
    for (int kk = 0; kk < 2; ++kk) {
      bf16x8 af[4], bfr[4];
      #pragma unroll
      for (int mi = 0; mi < 4; ++mi)
        af[mi] = *reinterpret_cast<const bf16x8*>(&lds_a[(wr + mi * 16 + lr) * 64 + kk * 32 + lg * 8]);
      #pragma unroll
      for (int ni = 0; ni < 4; ++ni)
        bfr[ni] = *reinterpret_cast<const bf16x8*>(&lds_b[(wc + ni * 16 + lr) * 64 + kk * 32 + lg * 8]);
      #pragma unroll
      for (int mi = 0; mi < 4; ++mi)
        #pragma unroll
        for (int ni = 0; ni < 4; ++ni)
          acc[mi][ni] = __builtin_amdgcn_mfma_f32_16x16x32_bf16(af[mi], bfr[ni], acc[mi][ni], 0, 0, 0);
    }
    __syncthreads();
  }

  if (mode == 0) {
    #pragma unroll
    for (int mi = 0; mi < 4; ++mi)
      #pragma unroll
      for (int ni = 0; ni < 4; ++ni)
        #pragma unroll
        for (int r = 0; r < 4; ++r) {
          int gm = tm + wr + mi * 16 + lg * 4 + r;
          int gn = tn + wc + ni * 16 + lr;
          float v = acc[mi][ni][r];
          unsigned short bv = f2bf(v);
          int bb = gm >> 11, l = gm & 2047;
          int tsel = gn >> 10, o = gn & 1023;
          int h = o >> 6, d = o & 63;
          if (tsel == 0)      qb[(((size_t)(bb * NHEAD + h)) * SEQ + l) * HD + d] = bv;
          else if (tsel == 1) kb[(((size_t)(bb * NHEAD + h)) * SEQ + l) * HD + d] = bv;
          else                vtb[(((size_t)(bb * NHEAD + h)) * HD + d) * SEQ + l] = bv;
        }
  } else {
    #pragma unroll
    for (int mi = 0; mi < 4; ++mi)
      #pragma unroll
      for (int ni = 0; ni < 4; ++ni)
        #pragma unroll
        for (int r = 0; r < 4; ++r) {
          int gm = tm + wr + mi * 16 + lg * 4 + r;
          int gn = tn + wc + ni * 16 + lr;
          outf[(size_t)gm * 1024 + gn] = acc[mi][ni][r] + bias[gn];
        }
  }
}

// ---------------- flash attention, causal, LDS-staged K/V ----------------
// Flat grid of 1024 blocks; XCD-aware mapping: xcd = id&7 owns 4 (b,h) pairs,
// within an XCD blocks run head-major with the heavy (diagonal-far) q-tiles
// first. 256 threads = 4 waves; wave w owns q-rows [qtile*64 + 16w, +16).
// K tile [kv=64][d=64] and V^T tile [d=64][kv=64] staged in LDS, XOR-swizzled
// via pre-swizzled global source (LDS[r][g] = G[r][g ^ (r&7)], 16B granules),
// double-buffered, one __syncthreads per tile.
__global__ __launch_bounds__(256) void attn_kernel(
    const unsigned short* __restrict__ qb,
    const unsigned short* __restrict__ kb,
    const unsigned short* __restrict__ vtb,
    unsigned short* __restrict__ ctxb)
{
  __shared__ unsigned short kt_lds[2][64 * 64];
  __shared__ unsigned short vt_lds[2][64 * 64];
  __shared__ unsigned short p_lds[4][16 * 64];

  const int t = threadIdx.x;
  const int wid = t >> 6;
  const int lane = t & 63;
  const int lr = lane & 15;
  const int lg = lane >> 4;

  const int id = blockIdx.x;
  const int xcd = id & 7;
  const int chunk = id >> 3;              // 0..127
  const int bh = xcd * 4 + (chunk >> 5);  // 4 (b,h) pairs per XCD
  const int qtile = 31 - (chunk & 31);    // heavy tiles dispatched first
  const int b = bh >> 4, h = bh & 15;
  const int qw = qtile * 64 + wid * 16;

  const float csc = (1.0f / 32.0f) * 1.44269504f;  // 1/sqrt(1024) * log2(e)

  // Q fragments, scale folded in (held in registers for the whole kernel)
  const unsigned short* Qp = qb + ((size_t)bh * SEQ + qw) * HD;
  bf16x8 aq[2];
  #pragma unroll
  for (int kk = 0; kk < 2; ++kk) {
    bf16x8 raw = *reinterpret_cast<const bf16x8*>(&Qp[lr * HD + kk * 32 + lg * 8]);
    #pragma unroll
    for (int j = 0; j < 8; ++j)
      aq[kk][j] = (short)f2bf(bf2f((unsigned short)raw[j]) * csc);
  }

  const unsigned short* Kp = kb + (size_t)bh * SEQ * HD;   // row kv, stride HD
  const unsigned short* Vp = vtb + (size_t)bh * HD * SEQ;  // row d,  stride SEQ
  const int sr_ = lane >> 3;   // 0..7: row within an 8-row wave chunk
  const int sg_ = lane & 7;    // 0..7: 16B granule

  auto stage = [&](int buf, int kv0) {
    #pragma unroll
    for (int i = 0; i < 2; ++i) {
      int r = i * 32 + wid * 8 + sr_;
      int g = sg_ ^ (r & 7);   // pre-swizzled source granule
      gload16(Kp + (size_t)(kv0 + r) * HD + g * 8, &kt_lds[buf][(i * 32 + wid * 8) * 64]);
      gload16(Vp + (size_t)r * SEQ + kv0 + g * 8, &vt_lds[buf][(i * 32 + wid * 8) * 64]);
    }
  };

  f32x4 oacc[4];
  #pragma unroll
  for (int ni = 0; ni < 4; ++ni) oacc[ni] = (f32x4){0.f, 0.f, 0.f, 0.f};
  float m_[4], ls[4];
  #pragma unroll
  for (int r = 0; r < 4; ++r) { m_[r] = -INFINITY; ls[r] = 0.f; }

  stage(0, 0);
  __syncthreads();
  int cur = 0;

  for (int kt = 0; kt <= qtile; ++kt) {
    const int kv0 = kt * 64;
    if (kt < qtile) stage(cur ^ 1, kv0 + 64);   // prefetch next tile

    // S = Q K^T (log2 domain; scale folded into Q)
    const char* kbase = (const char*)&kt_lds[cur][0];
    f32x4 s[4];
    #pragma unroll
    for (int ni = 0; ni < 4; ++ni) {
      int row = ni * 16 + lr;
      int xr = (row & 7) << 4;
      bf16x8 b0 = *reinterpret_cast<const bf16x8*>(kbase + (row * 128 + ((lg * 16) ^ xr)));
      bf16x8 b1 = *reinterpret_cast<const bf16x8*>(kbase + (row * 128 + ((64 + lg * 16) ^ xr)));
      s[ni] = (f32x4){0.f, 0.f, 0.f, 0.f};
      s[ni] = __builtin_amdgcn_mfma_f32_16x16x32_bf16(aq[0], b0, s[ni], 0, 0, 0);
      s[ni] = __builtin_amdgcn_mfma_f32_16x16x32_bf16(aq[1], b1, s[ni], 0, 0, 0);
    }

    if (kt == qtile) {   // causal mask, diagonal tile only
      #pragma unroll
      for (int ni = 0; ni < 4; ++ni)
        #pragma unroll
        for (int r = 0; r < 4; ++r) {
          int kv = kv0 + ni * 16 + lr;
          int qr = qw + lg * 4 + r;
          if (kv > qr) s[ni][r] = -INFINITY;
        }
    }

    float rmax[4];
    #pragma unroll
    for (int r = 0; r < 4; ++r)
      rmax[r] = fmaxf(fmaxf(s[0][r], s[1][r]), fmaxf(s[2][r], s[3][r]));
    #pragma unroll
    for (int off = 1; off < 16; off <<= 1)
      #pragma unroll
      for (int r = 0; r < 4; ++r) rmax[r] = fmaxf(rmax[r], __shfl_xor(rmax[r], off));

    float f[4], psum[4];
    #pragma unroll
    for (int r = 0; r < 4; ++r) {
      float mn = fmaxf(m_[r], rmax[r]);
      f[r] = exp2f(m_[r] - mn);
      m_[r] = mn;
      psum[r] = 0.f;
    }
    char* pbase = (char*)&p_lds[wid][0];
    #pragma unroll
    for (int ni = 0; ni < 4; ++ni)
      #pragma unroll
      for (int r = 0; r < 4; ++r) {
        float p = exp2f(s[ni][r] - m_[r]);
        psum[r] += p;
        int row = lg * 4 + r;
        *reinterpret_cast<unsigned short*>(
            pbase + ((row * 128 + ni * 32 + lr * 2) ^ ((row & 7) << 4))) = f2bf(p);
      }
    #pragma unroll
    for (int off = 1; off < 16; off <<= 1)
      #pragma unroll
      for (int r = 0; r < 4; ++r) psum[r] += __shfl_xor(psum[r], off);
    #pragma unroll
    for (int r = 0; r < 4; ++r) ls[r] = ls[r] * f[r] + psum[r];
    #pragma unroll
    for (int ni = 0; ni < 4; ++ni)
      #pragma unroll
      for (int r = 0; r < 4; ++r) oacc[ni][r] *= f[r];

    // P fragments (wave-private LDS; in-order DS within the wave, no barrier)
    int xp = (lr & 7) << 4;
    bf16x8 pa0 = *reinterpret_cast<const bf16x8*>(pbase + (lr * 128 + ((lg * 16) ^ xp)));
    bf16x8 pa1 = *reinterpret_cast<const bf16x8*>(pbase + (lr * 128 + ((64 + lg * 16) ^ xp)));

    // ctx += P V : B rows are d (V^T tile), K-contig in kv
    const char* vbase = (const char*)&vt_lds[cur][0];
    #pragma unroll
    for (int ni = 0; ni < 4; ++ni) {
      int row = ni * 16 + lr;
      int xr = (row & 7) << 4;
      bf16x8 v0 = *reinterpret_cast<const bf16x8*>(vbase + (row * 128 + ((lg * 16) ^ xr)));
      bf16x8 v1 = *reinterpret_cast<const bf16x8*>(vbase + (row * 128 + ((64 + lg * 16) ^ xr)));
      oacc[ni] = __builtin_amdgcn_mfma_f32_16x16x32_bf16(pa0, v0, oacc[ni], 0, 0, 0);
      oacc[ni] = __builtin_amdgcn_mfma_f32_16x16x32_bf16(pa1, v1, oacc[ni], 0, 0, 0);
    }

    __syncthreads();   // drains vmcnt: next tile staged; this buffer free
    cur ^= 1;
  }

  // write ctx [b][l][h*64+d] bf16
  #pragma unroll
  for (int ni = 0; ni < 4; ++ni)
    #pragma unroll
    for (int r = 0; r < 4; ++r) {
      int qr = qw + lg * 4 + r;
      int d = ni * 16 + lr;
      ctxb[((size_t)b * SEQ + qr) * 1024 + h * HD + d] = f2bf(oacc[ni][r] / ls[r]);
    }
}

extern "C" void kernel_launch(void* const* d_in, const int* in_sizes, int n_in,
                              void* d_out, int out_size, void* d_ws, size_t ws_size,
                              hipStream_t stream) {
  const float* x   = (const float*)d_in[0];
  const float* w_k = (const float*)d_in[1];
  const float* w_q = (const float*)d_in[2];
  const float* w_v = (const float*)d_in[3];
  const float* w_o = (const float*)d_in[4];
  const float* b_o = (const float*)d_in[5];
  float* out = (float*)d_out;

  char* ws = (char*)d_ws;
  unsigned short* xb   = (unsigned short*)(ws + 0);          //  8 MB [4096][1024]
  unsigned short* wqkv = (unsigned short*)(ws + 8388608);    //  6 MB [3072][1024]  (w_k;w_q;w_v)
  unsigned short* wob  = (unsigned short*)(ws + 14680064);   //  2 MB [1024][1024]
  unsigned short* qb   = (unsigned short*)(ws + 16777216);   //  8 MB [b][h][l][d]
  unsigned short* kb   = (unsigned short*)(ws + 25165824);   //  8 MB [b][h][l][d]
  unsigned short* vtb  = (unsigned short*)(ws + 33554432);   //  8 MB [b][h][d][l]
  unsigned short* ctxb = xb;                                  // reuse x region

  int n = M_TOT * 1024;
  cvt_kernel<<<n / 1024, 256, 0, stream>>>(x, xb, n);
  n = 1024 * 1024;
  cvt_kernel<<<n / 1024, 256, 0, stream>>>(w_k, wqkv, n);
  cvt_kernel<<<n / 1024, 256, 0, stream>>>(w_q, wqkv + 1048576, n);
  cvt_kernel<<<n / 1024, 256, 0, stream>>>(w_v, wqkv + 2097152, n);
  cvt_kernel<<<n / 1024, 256, 0, stream>>>(w_o, wob, n);

  // QKV: A = xb [4096][1024], B = wqkv [3072][1024]  (col block 0 -> Q via w_k, 1 -> K via w_q, 2 -> V)
  gemm_nt<<<dim3(32, 24), 256, 0, stream>>>(xb, wqkv, 1024, 0, qb, kb, vtb, nullptr, nullptr);

  attn_kernel<<<dim3(1024), 256, 0, stream>>>(qb, kb, vtb, ctxb);

  // out = ctx @ w_o^T + b_o
  gemm_nt<<<dim3(32, 8), 256, 0, stream>>>(ctxb, wob, 1024, 1, nullptr, nullptr, nullptr, b_o, out);
}

// Round 6
// 248.799 us; speedup vs baseline: 1.6644x; 1.0529x over previous
//
#include <hip/hip_runtime.h>
#include <hip/hip_bf16.h>

// MHA: x[2,2048,1024]; q = x@w_k^T (faithful swap), k = x@w_q^T, v = x@w_v^T
// scores = QK^T * (1/sqrt(1024)), causal mask, softmax, ctx = P@V
// out = ctx@w_o^T + b_o   (fp32 out)

typedef __attribute__((ext_vector_type(8))) short bf16x8;
typedef __attribute__((ext_vector_type(4))) float f32x4;

#define SEQ 2048
#define NHEAD 16
#define HD 64
#define M_TOT 4096   // B*L

static __device__ __forceinline__ unsigned short f2bf(float f) {
  unsigned int u = __float_as_uint(f);
  u += 0x7fff + ((u >> 16) & 1);          // RNE
  return (unsigned short)(u >> 16);
}
static __device__ __forceinline__ float bf2f(unsigned short u) {
  return __uint_as_float(((unsigned int)u) << 16);
}

static __device__ __forceinline__ void gload16(const unsigned short* g, unsigned short* l) {
  __builtin_amdgcn_global_load_lds(
      (const __attribute__((address_space(1))) unsigned int*)g,
      (__attribute__((address_space(3))) unsigned int*)l, 16, 0, 0);
}

// ---------------- fp32 -> bf16 convert, 4 elems/thread ----------------
__global__ void cvt_kernel(const float* __restrict__ in, unsigned short* __restrict__ out, int n) {
  int i = (blockIdx.x * blockDim.x + threadIdx.x) * 4;
  if (i >= n) return;
  float4 v = *reinterpret_cast<const float4*>(in + i);
  ushort4 o;
  o.x = f2bf(v.x); o.y = f2bf(v.y); o.z = f2bf(v.z); o.w = f2bf(v.w);
  *reinterpret_cast<ushort4*>(out + i) = o;
}

// ---------------- NT GEMM: C[M,N] = A[M,K] * B[N,K]^T ----------------
// 128x128 tile, 4 waves (2x2), BK=64, m97-style 2-barrier loop.
// mode 0: scatter to qb/kb ([b][h][l][d]) and vtb ([b][h][d][l]), bf16
// mode 1: out[m*1024+n] = acc + bias[n], fp32
__global__ __launch_bounds__(256) void gemm_nt(
    const unsigned short* __restrict__ A,
    const unsigned short* __restrict__ B,
    int K, int mode,
    unsigned short* __restrict__ qb,
    unsigned short* __restrict__ kb,
    unsigned short* __restrict__ vtb,
    const float* __restrict__ bias,
    float* __restrict__ outf)
{
  __shared__ unsigned short lds_a[128 * 64];
  __shared__ unsigned short lds_b[128 * 64];
  const int t = threadIdx.x;
  const int wid = t >> 6;
  const int lane = t & 63;
  const int lr = lane & 15;
  const int lg = lane >> 4;
  const int tm = blockIdx.x * 128;
  const int tn = blockIdx.y * 128;
  const int wr = (wid >> 1) * 64;
  const int wc = (wid & 1) * 64;

  const unsigned short* Ab = A + (size_t)tm * K;
  const unsigned short* Bb = B + (size_t)tn * K;
  const int srow = wid * 8 + (lane >> 3);   // row within a 32-row chunk
  const int scol = (lane & 7) * 8;          // bf16 col (16B granules)

  f32x4 acc[4][4];
  #pragma unroll
  for (int i = 0; i < 4; ++i)
    #pragma unroll
    for (int j = 0; j < 4; ++j) acc[i][j] = (f32x4){0.f, 0.f, 0.f, 0.f};

  for (int k0 = 0; k0 < K; k0 += 64) {
    #pragma unroll
    for (int i = 0; i < 4; ++i) {
      gload16(Ab + (size_t)(i * 32 + srow) * K + k0 + scol, &lds_a[(i * 32 + wid * 8) * 64]);
      gload16(Bb + (size_t)(i * 32 + srow) * K + k0 + scol, &lds_b[(i * 32 + wid * 8) * 64]);
    }
    __syncthreads();
    #pragma unroll
    for (int kk = 0; kk < 2; ++kk) {
      bf16x8 af[4], bfr[4];
      #pragma unroll
      for (int mi = 0; mi < 4; ++mi)
        af[mi] = *reinterpret_cast<const bf16x8*>(&lds_a[(wr + mi * 16 + lr) * 64 + kk * 32 + lg * 8]);
      #pragma unroll
      for (int ni = 0; ni < 4; ++ni)
        bfr[ni] = *reinterpret_cast<const bf16x8*>(&lds_b[(wc + ni * 16 + lr) * 64 + kk * 32 + lg * 8]);
      #pragma unroll
      for (int mi = 0; mi < 4; ++mi)
        #pragma unroll
        for (int ni = 0; ni < 4; ++ni)
          acc[mi][ni] = __builtin_amdgcn_mfma_f32_16x16x32_bf16(af[mi], bfr[ni], acc[mi][ni], 0, 0, 0);
    }
    __syncthreads();
  }

  if (mode == 0) {
    #pragma unroll
    for (int mi = 0; mi < 4; ++mi)
      #pragma unroll
      for (int ni = 0; ni < 4; ++ni)
        #pragma unroll
        for (int r = 0; r < 4; ++r) {
          int gm = tm + wr + mi * 16 + lg * 4 + r;
          int gn = tn + wc + ni * 16 + lr;
          float v = acc[mi][ni][r];
          unsigned short bv = f2bf(v);
          int bb = gm >> 11, l = gm & 2047;
          int tsel = gn >> 10, o = gn & 1023;
          int h = o >> 6, d = o & 63;
          if (tsel == 0)      qb[(((size_t)(bb * NHEAD + h)) * SEQ + l) * HD + d] = bv;
          else if (tsel == 1) kb[(((size_t)(bb * NHEAD + h)) * SEQ + l) * HD + d] = bv;
          else                vtb[(((size_t)(bb * NHEAD + h)) * HD + d) * SEQ + l] = bv;
        }
  } else {
    #pragma unroll
    for (int mi = 0; mi < 4; ++mi)
      #pragma unroll
      for (int ni = 0; ni < 4; ++ni)
        #pragma unroll
        for (int r = 0; r < 4; ++r) {
          int gm = tm + wr + mi * 16 + lg * 4 + r;
          int gn = tn + wc + ni * 16 + lr;
          outf[(size_t)gm * 1024 + gn] = acc[mi][ni][r] + bias[gn];
        }
  }
}

// ---------------- flash attention, causal, LDS-staged K/V ----------------
// Grid 512 blocks: xcd = id&7 owns 4 (b,h) pairs; each block processes TWO
// q-tiles (31-pair, pair) sequentially -> exactly 33 KV-tile iterations per
// block (perfect load balance; no CU drain). 256 threads = 4 waves; wave w
// owns q-rows [qtile*64 + 16w, +16). K tile [kv=64][d=64] and V^T tile
// [d=64][kv=64] staged in LDS via global_load_lds w=16, XOR-swizzled through
// pre-swizzled global source (LDS[r][g] = G[r][g ^ (r&7)], 16B granules),
// double-buffered, one __syncthreads per tile. Defer-max (THR=8): skip the
// O/ls rescale unless the running max grew by >8 (rare; scores are tiny).
__global__ __launch_bounds__(256) void attn_kernel(
    const unsigned short* __restrict__ qb,
    const unsigned short* __restrict__ kb,
    const unsigned short* __restrict__ vtb,
    unsigned short* __restrict__ ctxb)
{
  __shared__ unsigned short kt_lds[2][64 * 64];
  __shared__ unsigned short vt_lds[2][64 * 64];
  __shared__ unsigned short p_lds[4][16 * 64];

  const int t = threadIdx.x;
  const int wid = t >> 6;
  const int lane = t & 63;
  const int lr = lane & 15;
  const int lg = lane >> 4;

  const int id = blockIdx.x;
  const int xcd = id & 7;
  const int chunk = id >> 3;              // 0..63
  const int bh = xcd * 4 + (chunk >> 4);  // 4 (b,h) pairs per XCD
  const int pair = chunk & 15;            // 0..15
  const int b = bh >> 4, h = bh & 15;

  const float csc = (1.0f / 32.0f) * 1.44269504f;  // 1/sqrt(1024) * log2(e)

  const unsigned short* Kp = kb + (size_t)bh * SEQ * HD;   // row kv, stride HD
  const unsigned short* Vp = vtb + (size_t)bh * HD * SEQ;  // row d,  stride SEQ
  const int sr_ = lane >> 3;   // 0..7: row within an 8-row wave chunk
  const int sg_ = lane & 7;    // 0..7: 16B granule

  auto stage = [&](int buf, int kv0) {
    #pragma unroll
    for (int i = 0; i < 2; ++i) {
      int r = i * 32 + wid * 8 + sr_;
      int g = sg_ ^ (r & 7);   // pre-swizzled source granule
      gload16(Kp + (size_t)(kv0 + r) * HD + g * 8, &kt_lds[buf][(i * 32 + wid * 8) * 64]);
      gload16(Vp + (size_t)r * SEQ + kv0 + g * 8, &vt_lds[buf][(i * 32 + wid * 8) * 64]);
    }
  };

  for (int ph = 0; ph < 2; ++ph) {
    const int qtile = (ph == 0) ? (31 - pair) : pair;
    const int qw = qtile * 64 + wid * 16;

    // Q fragments, scale folded in
    const unsigned short* Qp = qb + ((size_t)bh * SEQ + qw) * HD;
    bf16x8 aq[2];
    #pragma unroll
    for (int kk = 0; kk < 2; ++kk) {
      bf16x8 raw = *reinterpret_cast<const bf16x8*>(&Qp[lr * HD + kk * 32 + lg * 8]);
      #pragma unroll
      for (int j = 0; j < 8; ++j)
        aq[kk][j] = (short)f2bf(bf2f((unsigned short)raw[j]) * csc);
    }

    f32x4 oacc[4];
    #pragma unroll
    for (int ni = 0; ni < 4; ++ni) oacc[ni] = (f32x4){0.f, 0.f, 0.f, 0.f};
    float m_[4], ls[4];
    #pragma unroll
    for (int r = 0; r < 4; ++r) { m_[r] = -INFINITY; ls[r] = 0.f; }

    stage(0, 0);
    __syncthreads();
    int cur = 0;

    for (int kt = 0; kt <= qtile; ++kt) {
      const int kv0 = kt * 64;
      if (kt < qtile) stage(cur ^ 1, kv0 + 64);   // prefetch next tile

      // S = Q K^T (log2 domain; scale folded into Q)
      const char* kbase = (const char*)&kt_lds[cur][0];
      f32x4 s[4];
      #pragma unroll
      for (int ni = 0; ni < 4; ++ni) {
        int row = ni * 16 + lr;
        int xr = (row & 7) << 4;
        bf16x8 b0 = *reinterpret_cast<const bf16x8*>(kbase + (row * 128 + ((lg * 16) ^ xr)));
        bf16x8 b1 = *reinterpret_cast<const bf16x8*>(kbase + (row * 128 + ((64 + lg * 16) ^ xr)));
        s[ni] = (f32x4){0.f, 0.f, 0.f, 0.f};
        s[ni] = __builtin_amdgcn_mfma_f32_16x16x32_bf16(aq[0], b0, s[ni], 0, 0, 0);
        s[ni] = __builtin_amdgcn_mfma_f32_16x16x32_bf16(aq[1], b1, s[ni], 0, 0, 0);
      }

      if (kt == qtile) {   // causal mask, diagonal tile only
        #pragma unroll
        for (int ni = 0; ni < 4; ++ni)
          #pragma unroll
          for (int r = 0; r < 4; ++r) {
            int kv = kv0 + ni * 16 + lr;
            int qr = qw + lg * 4 + r;
            if (kv > qr) s[ni][r] = -INFINITY;
          }
      }

      float rmax[4];
      #pragma unroll
      for (int r = 0; r < 4; ++r)
        rmax[r] = fmaxf(fmaxf(s[0][r], s[1][r]), fmaxf(s[2][r], s[3][r]));
      #pragma unroll
      for (int off = 1; off < 16; off <<= 1)
        #pragma unroll
        for (int r = 0; r < 4; ++r) rmax[r] = fmaxf(rmax[r], __shfl_xor(rmax[r], off));

      // defer-max: rescale only when max grew by > 8 (P bounded by 2^8)
      bool need = (rmax[0] > m_[0] + 8.f) | (rmax[1] > m_[1] + 8.f) |
                  (rmax[2] > m_[2] + 8.f) | (rmax[3] > m_[3] + 8.f);
      if (__any(need)) {
        #pragma unroll
        for (int r = 0; r < 4; ++r) {
          float mn = fmaxf(m_[r], rmax[r]);
          float f = exp2f(m_[r] - mn);
          m_[r] = mn;
          ls[r] *= f;
          #pragma unroll
          for (int ni = 0; ni < 4; ++ni) oacc[ni][r] *= f;
        }
      }

      float psum[4] = {0.f, 0.f, 0.f, 0.f};
      char* pbase = (char*)&p_lds[wid][0];
      #pragma unroll
      for (int ni = 0; ni < 4; ++ni)
        #pragma unroll
        for (int r = 0; r < 4; ++r) {
          float p = exp2f(s[ni][r] - m_[r]);
          psum[r] += p;
          int row = lg * 4 + r;
          *reinterpret_cast<unsigned short*>(
              pbase + ((row * 128 + ni * 32 + lr * 2) ^ ((row & 7) << 4))) = f2bf(p);
        }
      #pragma unroll
      for (int off = 1; off < 16; off <<= 1)
        #pragma unroll
        for (int r = 0; r < 4; ++r) psum[r] += __shfl_xor(psum[r], off);
      #pragma unroll
      for (int r = 0; r < 4; ++r) ls[r] += psum[r];

      // P fragments (wave-private LDS; in-order DS within the wave)
      int xp = (lr & 7) << 4;
      bf16x8 pa0 = *reinterpret_cast<const bf16x8*>(pbase + (lr * 128 + ((lg * 16) ^ xp)));
      bf16x8 pa1 = *reinterpret_cast<const bf16x8*>(pbase + (lr * 128 + ((64 + lg * 16) ^ xp)));

      // ctx += P V : B rows are d (V^T tile), K-contig in kv
      const char* vbase = (const char*)&vt_lds[cur][0];
      #pragma unroll
      for (int ni = 0; ni < 4; ++ni) {
        int row = ni * 16 + lr;
        int xr = (row & 7) << 4;
        bf16x8 v0 = *reinterpret_cast<const bf16x8*>(vbase + (row * 128 + ((lg * 16) ^ xr)));
        bf16x8 v1 = *reinterpret_cast<const bf16x8*>(vbase + (row * 128 + ((64 + lg * 16) ^ xr)));
        oacc[ni] = __builtin_amdgcn_mfma_f32_16x16x32_bf16(pa0, v0, oacc[ni], 0, 0, 0);
        oacc[ni] = __builtin_amdgcn_mfma_f32_16x16x32_bf16(pa1, v1, oacc[ni], 0, 0, 0);
      }

      __syncthreads();   // drains vmcnt: next tile staged; this buffer free
      cur ^= 1;
    }

    // write ctx [b][l][h*64+d] bf16
    #pragma unroll
    for (int ni = 0; ni < 4; ++ni)
      #pragma unroll
      for (int r = 0; r < 4; ++r) {
        int qr = qw + lg * 4 + r;
        int d = ni * 16 + lr;
        ctxb[((size_t)b * SEQ + qr) * 1024 + h * HD + d] = f2bf(oacc[ni][r] / ls[r]);
      }
  }
}

extern "C" void kernel_launch(void* const* d_in, const int* in_sizes, int n_in,
                              void* d_out, int out_size, void* d_ws, size_t ws_size,
                              hipStream_t stream) {
  const float* x   = (const float*)d_in[0];
  const float* w_k = (const float*)d_in[1];
  const float* w_q = (const float*)d_in[2];
  const float* w_v = (const float*)d_in[3];
  const float* w_o = (const float*)d_in[4];
  const float* b_o = (const float*)d_in[5];
  float* out = (float*)d_out;

  char* ws = (char*)d_ws;
  unsigned short* xb   = (unsigned short*)(ws + 0);          //  8 MB [4096][1024]
  unsigned short* wqkv = (unsigned short*)(ws + 8388608);    //  6 MB [3072][1024]  (w_k;w_q;w_v)
  unsigned short* wob  = (unsigned short*)(ws + 14680064);   //  2 MB [1024][1024]
  unsigned short* qb   = (unsigned short*)(ws + 16777216);   //  8 MB [b][h][l][d]
  unsigned short* kb   = (unsigned short*)(ws + 25165824);   //  8 MB [b][h][l][d]
  unsigned short* vtb  = (unsigned short*)(ws + 33554432);   //  8 MB [b][h][d][l]
  unsigned short* ctxb = xb;                                  // reuse x region

  int n = M_TOT * 1024;
  cvt_kernel<<<n / 1024, 256, 0, stream>>>(x, xb, n);
  n = 1024 * 1024;
  cvt_kernel<<<n / 1024, 256, 0, stream>>>(w_k, wqkv, n);
  cvt_kernel<<<n / 1024, 256, 0, stream>>>(w_q, wqkv + 1048576, n);
  cvt_kernel<<<n / 1024, 256, 0, stream>>>(w_v, wqkv + 2097152, n);
  cvt_kernel<<<n / 1024, 256, 0, stream>>>(w_o, wob, n);

  // QKV: A = xb [4096][1024], B = wqkv [3072][1024]  (col block 0 -> Q via w_k, 1 -> K via w_q, 2 -> V)
  gemm_nt<<<dim3(32, 24), 256, 0, stream>>>(xb, wqkv, 1024, 0, qb, kb, vtb, nullptr, nullptr);

  attn_kernel<<<dim3(512), 256, 0, stream>>>(qb, kb, vtb, ctxb);

  // out = ctx @ w_o^T + b_o
  gemm_nt<<<dim3(32, 8), 256, 0, stream>>>(ctxb, wob, 1024, 1, nullptr, nullptr, nullptr, b_o, out);
}